// Round 4
// baseline (223.034 us; speedup 1.0000x reference)
//
#include <hip/hip_runtime.h>
#include <math.h>

#define EPS 1e-5f

__device__ __forceinline__ float wave_sum(float v) {
  v += __shfl_down(v, 32);
  v += __shfl_down(v, 16);
  v += __shfl_down(v, 8);
  v += __shfl_down(v, 4);
  v += __shfl_down(v, 2);
  v += __shfl_down(v, 1);
  return v;
}

__device__ __forceinline__ float silu_f(float v) { return v / (1.f + __expf(-v)); }
__device__ __forceinline__ float sigm_f(float v) { return 1.f / (1.f + __expf(-v)); }

__device__ __forceinline__ int bitrev6(int v) {
  return ((v & 1) << 5) | ((v & 2) << 3) | ((v & 4) << 1) |
         ((v & 8) >> 1) | ((v & 16) >> 3) | ((v & 32) >> 5);
}

// ---------------------------------------------------------------------------
// Kernel A: per-(b,c) mean |2D-DFT| + spatial mean.
// R3: (a) two real rows packed as one complex FFT, unpacked via the
// conjugate-mirror lane (row pass: 8 FFTs/wave, was 16); (b) row spectra
// stored in NATURAL kv order (bit-reversed scatter store; banks (f+h)%32 ->
// 2-way, free), so column conjugate symmetry applies: FFT only kv=0..32,
// weight 2 for kv=1..31 (col pass ~8.5 FFTs/wave, was 16).
// ---------------------------------------------------------------------------
__global__ __launch_bounds__(256) void k_dft(const float* __restrict__ x,
                                             float* __restrict__ energy,
                                             float* __restrict__ meanx) {
  __shared__ float re1[64 * 65];   // [kv natural][h]
  __shared__ float im1[64 * 65];
  __shared__ float redA[4], redB[4];
  const int bc = blockIdx.x;       // b*64 + c
  const int tid = threadIdx.x;
  const int lane = tid & 63;
  const int wv = tid >> 6;         // wave 0..3
  const float* xp = x + (size_t)bc * 4096;

  // DIF stage twiddles (per lane, registers)
  float twc[6], tws[6];
#pragma unroll
  for (int s = 0; s < 6; ++s) {
    int half = 32 >> s;
    if (lane & half) {
      float ang = -6.283185307179586f * (float)((lane & (half - 1)) << s) / 64.f;
      float sv, cv;
      __sincosf(ang, &sv, &cv);
      twc[s] = cv;
      tws[s] = sv;
    } else {
      twc[s] = 1.f;
      tws[s] = 0.f;
    }
  }

  const int f = bitrev6(lane);          // frequency this lane ends up holding
  const int fm = (64 - f) & 63;         // mirror frequency
  const int plane = bitrev6(fm);        // lane holding the mirror frequency

  // ---- row pass: rows (2r, 2r+1) as one complex FFT ----
  float lsum = 0.f;
#pragma unroll 1
  for (int rp = 0; rp < 8; ++rp) {
    const int h0 = wv * 16 + rp * 2;
    float zr = xp[h0 * 64 + lane];
    float zi = xp[(h0 + 1) * 64 + lane];
    lsum += zr + zi;
#pragma unroll
    for (int s = 0; s < 6; ++s) {
      const int half = 32 >> s;
      const bool up = (lane & half) != 0;
      float pr = __shfl_xor(zr, half);
      float pi = __shfl_xor(zi, half);
      float tr = up ? pr - zr : zr + pr;
      float ti = up ? pi - zi : zi + pi;
      const float c = twc[s], sn = tws[s];
      zr = tr * c - ti * sn;
      zi = tr * sn + ti * c;
    }
    // lane holds Z[f]; mirror Z[fm] lives in lane `plane`
    float mr = __shfl(zr, plane);
    float mi = __shfl(zi, plane);
    // X_a[f] = (Z[f] + conj(Z[fm]))/2 ; X_b[f] = (Z[f] - conj(Z[fm]))/(2i)
    float ar = 0.5f * (zr + mr), ai = 0.5f * (zi - mi);
    float br = 0.5f * (zi + mi), bi = 0.5f * (mr - zr);
    re1[f * 65 + h0] = ar;
    im1[f * 65 + h0] = ai;
    re1[f * 65 + h0 + 1] = br;
    im1[f * 65 + h0 + 1] = bi;
  }
  __syncthreads();

  // ---- column pass: kv = 0..32 only; weight 2 for interior kv ----
  float msum = 0.f;
#pragma unroll 1
  for (int i = 0; i < 9; ++i) {
    const int kv = wv + 4 * i;          // wave-uniform
    if (kv > 32) break;                 // wave-uniform exit (tail iteration)
    const float wgt = (kv == 0 || kv == 32) ? 1.f : 2.f;
    float ar = re1[kv * 65 + lane];
    float ai = im1[kv * 65 + lane];
#pragma unroll
    for (int s = 0; s < 6; ++s) {
      const int half = 32 >> s;
      const bool up = (lane & half) != 0;
      float pr = __shfl_xor(ar, half);
      float pi = __shfl_xor(ai, half);
      float tr = up ? pr - ar : ar + pr;
      float ti = up ? pi - ai : ai + pi;
      const float c = twc[s], sn = tws[s];
      ar = tr * c - ti * sn;
      ai = tr * sn + ti * c;
    }
    msum += wgt * sqrtf(ar * ar + ai * ai);
  }

  msum = wave_sum(msum);
  lsum = wave_sum(lsum);
  if (lane == 0) { redA[wv] = msum; redB[wv] = lsum; }
  __syncthreads();
  if (tid == 0) {
    float e = redA[0] + redA[1] + redA[2] + redA[3];
    float m = redB[0] + redB[1] + redB[2] + redB[3];
    energy[bc] = e * (1.f / 4096.f);
    meanx[bc] = m * (1.f / 4096.f);
  }
}

// ---------------------------------------------------------------------------
// Kernel B: per-batch channel attention head (unchanged).
// ---------------------------------------------------------------------------
__global__ __launch_bounds__(64) void k_attn(
    const float* __restrict__ energy, const float* __restrict__ meanx,
    const float* __restrict__ ex_w, const float* __restrict__ ey_w,
    const float* __restrict__ ez_w, const float* __restrict__ ff_w,
    const float* __restrict__ ff_b, const float* __restrict__ g1_w,
    const float* __restrict__ g1_b, const float* __restrict__ g2_w,
    const float* __restrict__ g2_b, float* __restrict__ s2) {
  __shared__ float e[64], mx[64], my[64], mz[64];
  __shared__ float ax[64], ay[64], az[64], af[64], h1[16];
  const int b = blockIdx.x;
  const int c = threadIdx.x;
  e[c] = energy[b * 64 + c];
  mx[c] = meanx[b * 64 + c];
  __syncthreads();
  int rank = 0;
  float ec = e[c];
  for (int i = 0; i < 64; ++i) {
    float ei = e[i];
    rank += (ei > ec) || (ei == ec && i < c);
  }
  float mask = (rank < 32) ? 1.f : 0.f;
  my[c] = mx[c] * mask;
  mz[c] = mx[c] * (1.f - mask);
  __syncthreads();
  {
    float l, r, m;
    l = (c > 0) ? mx[c - 1] : 0.f; m = mx[c]; r = (c < 63) ? mx[c + 1] : 0.f;
    ax[c] = sigm_f(ex_w[0] * l + ex_w[1] * m + ex_w[2] * r);
    l = (c > 0) ? my[c - 1] : 0.f; m = my[c]; r = (c < 63) ? my[c + 1] : 0.f;
    ay[c] = sigm_f(ey_w[0] * l + ey_w[1] * m + ey_w[2] * r);
    l = (c > 0) ? mz[c - 1] : 0.f; m = mz[c]; r = (c < 63) ? mz[c + 1] : 0.f;
    az[c] = sigm_f(ez_w[0] * l + ez_w[1] * m + ez_w[2] * r);
  }
  __syncthreads();
  {
    int g = c >> 4;
    float acc = ff_b[c];
#pragma unroll
    for (int i = 0; i < 32; ++i) {
      int ch = g * 32 + i;
      float v = (ch < 64) ? ay[ch] : az[ch - 64];
      acc = fmaf(v, ff_w[c * 32 + i], acc);
    }
    af[c] = acc;
  }
  __syncthreads();
  if (c < 16) {
    float a = g1_b[c];
#pragma unroll
    for (int i = 0; i < 64; ++i) a = fmaf(af[i], g1_w[c * 128 + i], a);
#pragma unroll
    for (int i = 0; i < 64; ++i) a = fmaf(ax[i], g1_w[c * 128 + 64 + i], a);
    h1[c] = silu_f(a);
  }
  __syncthreads();
  float gv = g2_b[c];
#pragma unroll
  for (int o = 0; o < 16; ++o) gv = fmaf(h1[o], g2_w[c * 16 + o], gv);
  gv = sigm_f(gv);
  s2[b * 64 + c] = gv * af[c] + (1.f - gv) * ax[c];
}

// ---------------------------------------------------------------------------
// Kernel C: fused ReceptiveFieldAttentionConv.
// R3: back to LDS-broadcast weights but (a) float4-packed (pad 9->12,
// ds_read_b128), sc bias packed at slot [9] of each filter row; (b) P=2
// pixels per thread (vertical pair) so every weight read amortizes 2x and
// the 3x3 neighborhoods share 2 of 4 rows; (c) x staged in a zero-padded
// LDS tile (immediate-offset ds reads, no predication).
// Block = 128 thr (2 waves), 4-row band; grid = 8b x 4g x 16 bands = 512.
// ---------------------------------------------------------------------------
__global__ __launch_bounds__(128) void k_rfa(
    const float* __restrict__ x,
    const float* __restrict__ sc_w, const float* __restrict__ sc_b,
    const float* __restrict__ ac_w, const float* __restrict__ ac_b,
    const float* __restrict__ oc_w, const float* __restrict__ oc_b,
    const float* __restrict__ bn_g, const float* __restrict__ bn_b,
    const float* __restrict__ bn_m, const float* __restrict__ bn_v,
    float* __restrict__ xrfa) {
  __shared__ __align__(16) float xs[16 * 6 * 66];      // 6336
  __shared__ __align__(16) float scwp[16 * 9 * 12];    // 1728: taps 0..8, bias at [9]
  __shared__ __align__(16) float mp[16 * 24];          // 384: acw at [0..8], acb at [12..20]
  __shared__ __align__(16) float ocwp[16 * 16 * 12];   // 3072
  const int blk = blockIdx.x;
  const int band = blk & 15;
  const int g = (blk >> 4) & 3;
  const int b = blk >> 6;
  const int tid = threadIdx.x;
  const int lane = tid & 63;
  const int wv = tid >> 6;      // 0..1
  const int h0 = band * 4;

  // ---- stage x tile: 16 ch x rows (h0-1..h0+4) x 66 cols (zero-padded) ----
  for (int p = wv; p < 96; p += 2) {
    int ch = p / 6, lrow = p - ch * 6;
    int h = h0 - 1 + lrow;
    float v = 0.f;
    if (h >= 0 && h < 64)
      v = x[((size_t)(b * 64 + g * 16 + ch)) * 4096 + h * 64 + lane];
    xs[ch * 396 + lrow * 66 + lane + 1] = v;
  }
  for (int i = tid; i < 192; i += 128) {
    int ch = i / 12;
    int rem = i - ch * 12;
    int r = rem >> 1;
    xs[ch * 396 + r * 66 + (i & 1) * 65] = 0.f;
  }
  // ---- stage packed weights ----
  for (int i = tid; i < 1296; i += 128) {
    int icg = i / 81, rem = i - icg * 81;
    int j = rem / 9, t = rem - j * 9;
    scwp[icg * 108 + j * 12 + t] = sc_w[(g * 144 + icg * 9 + j) * 9 + t];
  }
  for (int i = tid; i < 144; i += 128) {
    int icg = i / 9, j = i - icg * 9;
    scwp[icg * 108 + j * 12 + 9] = sc_b[g * 144 + i];
    mp[icg * 24 + j] = ac_w[g * 144 + i];
    mp[icg * 24 + 12 + j] = ac_b[g * 144 + i];
  }
  for (int i = tid; i < 2304; i += 128) {
    int oco = i / 144, rem = i - oco * 144;
    int icg = rem / 9, j = rem - icg * 9;
    ocwp[icg * 192 + oco * 12 + j] = oc_w[((g * 16 + oco) * 16 + icg) * 9 + j];
  }
  __syncthreads();

  // thread -> 2 pixels: rows r0 = h0 + wv*2, r0+1 ; col = lane
  const int w = lane;
  float acc0[16], acc1[16];
#pragma unroll
  for (int i = 0; i < 16; ++i) { acc0[i] = 0.f; acc1[i] = 0.f; }

#pragma unroll 1
  for (int icg = 0; icg < 16; ++icg) {
    // 4x3 neighborhood window (rows wv*2 .. wv*2+3 in tile coords)
    const int xb = icg * 396 + (wv * 2) * 66 + w;
    float n[12];
#pragma unroll
    for (int rr = 0; rr < 4; ++rr)
#pragma unroll
      for (int cc = 0; cc < 3; ++cc)
        n[rr * 3 + cc] = xs[xb + rr * 66 + cc];
    float rs0 = n[0] + n[1] + n[2];
    float rs1 = n[3] + n[4] + n[5];
    float rs2 = n[6] + n[7] + n[8];
    float rs3 = n[9] + n[10] + n[11];
    float ap0 = (rs0 + rs1 + rs2) * (1.f / 9.f);
    float ap1 = (rs1 + rs2 + rs3) * (1.f / 9.f);

    float aw[12], ab[12];
    *(float4*)&aw[0] = *(const float4*)&mp[icg * 24];
    *(float4*)&aw[4] = *(const float4*)&mp[icg * 24 + 4];
    *(float4*)&aw[8] = *(const float4*)&mp[icg * 24 + 8];
    *(float4*)&ab[0] = *(const float4*)&mp[icg * 24 + 12];
    *(float4*)&ab[4] = *(const float4*)&mp[icg * 24 + 16];
    *(float4*)&ab[8] = *(const float4*)&mp[icg * 24 + 20];

    float f0[9], f1[9], a0[9], a1[9];
    float amax0 = -1e30f, amax1 = -1e30f;
#pragma unroll
    for (int j = 0; j < 9; ++j) {
      float wt[12];
      *(float4*)&wt[0] = *(const float4*)&scwp[icg * 108 + j * 12];
      *(float4*)&wt[4] = *(const float4*)&scwp[icg * 108 + j * 12 + 4];
      *(float4*)&wt[8] = *(const float4*)&scwp[icg * 108 + j * 12 + 8];
      float p0 = wt[9], p1 = wt[9];   // bias
#pragma unroll
      for (int t = 0; t < 9; ++t) {
        p0 = fmaf(n[t], wt[t], p0);       // rows 0..2
        p1 = fmaf(n[t + 3], wt[t], p1);   // rows 1..3
      }
      f0[j] = silu_f(p0);
      f1[j] = silu_f(p1);
      float v0 = fmaf(ap0, aw[j], ab[j]);
      float v1 = fmaf(ap1, aw[j], ab[j]);
      a0[j] = v0; a1[j] = v1;
      amax0 = fmaxf(amax0, v0);
      amax1 = fmaxf(amax1, v1);
    }
    float es0 = 0.f, es1 = 0.f;
    float p0[9], p1[9];
#pragma unroll
    for (int j = 0; j < 9; ++j) {
      float e0 = __expf(a0[j] - amax0);
      float e1 = __expf(a1[j] - amax1);
      es0 += e0; es1 += e1;
      p0[j] = f0[j] * e0;
      p1[j] = f1[j] * e1;
    }
    float i0 = __fdividef(1.f, es0);
    float i1 = __fdividef(1.f, es1);
#pragma unroll
    for (int j = 0; j < 9; ++j) { p0[j] *= i0; p1[j] *= i1; }

#pragma unroll
    for (int oco = 0; oco < 16; ++oco) {
      float ov[12];
      *(float4*)&ov[0] = *(const float4*)&ocwp[icg * 192 + oco * 12];
      *(float4*)&ov[4] = *(const float4*)&ocwp[icg * 192 + oco * 12 + 4];
      *(float4*)&ov[8] = *(const float4*)&ocwp[icg * 192 + oco * 12 + 8];
      float s0 = 0.f, s1 = 0.f;
#pragma unroll
      for (int j = 0; j < 9; ++j) {
        s0 = fmaf(p0[j], ov[j], s0);
        s1 = fmaf(p1[j], ov[j], s1);
      }
      acc0[oco] += s0;
      acc1[oco] += s1;
    }
  }

  const int r0 = h0 + wv * 2;
  float* op = xrfa + ((size_t)(b * 64 + g * 16)) * 4096 + r0 * 64 + w;
#pragma unroll
  for (int oco = 0; oco < 16; ++oco) {
    int oc = g * 16 + oco;
    float s = bn_g[oc] * rsqrtf(bn_v[oc] + EPS);
    float bb = bn_b[oc] - bn_m[oc] * s;
    float ob = oc_b[oc];
    float v0 = fmaf(acc0[oco] + ob, s, bb);
    float v1 = fmaf(acc1[oco] + ob, s, bb);
    op[oco * 4096] = silu_f(v0);
    op[oco * 4096 + 64] = silu_f(v1);
  }
}

// ---------------------------------------------------------------------------
// Kernel D: final 1x1 conv + BN + SiLU (unchanged from R2).
// ---------------------------------------------------------------------------
__global__ __launch_bounds__(256) void k_fuse(
    const float* __restrict__ x, const float* __restrict__ xrfa,
    const float* __restrict__ s2, const float* __restrict__ fu_w,
    const float* __restrict__ fu_b, const float* __restrict__ bn_g,
    const float* __restrict__ bn_b, const float* __restrict__ bn_m,
    const float* __restrict__ bn_v, float* __restrict__ out) {
  __shared__ float red[3 * 64 * 33];
  const int blk = blockIdx.x;
  const int tid = threadIdx.x;
  const int sloc = tid & 63;
  const int chunk = __builtin_amdgcn_readfirstlane(tid >> 6);
  const int b = blk >> 6;
  const int sp = (blk & 63) * 64 + sloc;
  const int cb = (chunk & 1) * 32;
  const int wb = chunk * 32;

  const float* src = (chunk < 2) ? xrfa : x;
  const float* ip = src + ((size_t)(b * 64 + cb)) * 4096 + sp;
  float inv[32];
  if (chunk < 2) {
#pragma unroll
    for (int i = 0; i < 32; ++i) inv[i] = ip[i * 4096];
  } else {
#pragma unroll
    for (int i = 0; i < 32; ++i) inv[i] = ip[i * 4096] * s2[b * 64 + cb + i];
  }

  float acc[32];
#pragma unroll
  for (int oc = 0; oc < 32; ++oc) {
    float a = 0.f;
#pragma unroll
    for (int i = 0; i < 32; ++i) a = fmaf(inv[i], fu_w[oc * 128 + wb + i], a);
    acc[oc] = a;
  }

  if (chunk != 0) {
    float* rp = &red[(chunk - 1) * 2112 + sloc * 33];
#pragma unroll
    for (int oc = 0; oc < 32; ++oc) rp[oc] = acc[oc];
  }
  __syncthreads();
  if (chunk == 0) {
#pragma unroll
    for (int oc = 0; oc < 32; ++oc)
      acc[oc] += red[sloc * 33 + oc] + red[2112 + sloc * 33 + oc] +
                 red[4224 + sloc * 33 + oc];
    float* op = out + ((size_t)b * 32) * 4096 + sp;
#pragma unroll
    for (int oc = 0; oc < 32; ++oc) {
      float s = bn_g[oc] * rsqrtf(bn_v[oc] + EPS);
      float v = acc[oc] + fu_b[oc];
      v = fmaf(v, s, bn_b[oc] - bn_m[oc] * s);
      op[oc * 4096] = silu_f(v);
    }
  }
}

extern "C" void kernel_launch(void* const* d_in, const int* in_sizes, int n_in,
                              void* d_out, int out_size, void* d_ws, size_t ws_size,
                              hipStream_t stream) {
  const float* x       = (const float*)d_in[0];
  const float* sc_w    = (const float*)d_in[1];
  const float* sc_b    = (const float*)d_in[2];
  const float* ac_w    = (const float*)d_in[3];
  const float* ac_b    = (const float*)d_in[4];
  const float* oc_w    = (const float*)d_in[5];
  const float* oc_b    = (const float*)d_in[6];
  const float* oc_bn_g = (const float*)d_in[7];
  const float* oc_bn_b = (const float*)d_in[8];
  const float* oc_bn_m = (const float*)d_in[9];
  const float* oc_bn_v = (const float*)d_in[10];
  const float* ex_w    = (const float*)d_in[11];
  const float* ey_w    = (const float*)d_in[12];
  const float* ez_w    = (const float*)d_in[13];
  const float* ff_w    = (const float*)d_in[14];
  const float* ff_b    = (const float*)d_in[15];
  const float* g1_w    = (const float*)d_in[16];
  const float* g1_b    = (const float*)d_in[17];
  const float* g2_w    = (const float*)d_in[18];
  const float* g2_b    = (const float*)d_in[19];
  const float* fu_w    = (const float*)d_in[20];
  const float* fu_b    = (const float*)d_in[21];
  const float* fu_bn_g = (const float*)d_in[22];
  const float* fu_bn_b = (const float*)d_in[23];
  const float* fu_bn_m = (const float*)d_in[24];
  const float* fu_bn_v = (const float*)d_in[25];

  float* ws     = (float*)d_ws;
  float* energy = ws;            // 512 floats
  float* meanx  = ws + 512;      // 512 floats
  float* s2     = ws + 1024;     // 512 floats
  float* xrfa   = ws + 2048;     // 8*64*4096 floats

  k_dft<<<512, 256, 0, stream>>>(x, energy, meanx);
  k_attn<<<8, 64, 0, stream>>>(energy, meanx, ex_w, ey_w, ez_w,
                               ff_w, ff_b, g1_w, g1_b, g2_w, g2_b, s2);
  k_rfa<<<512, 128, 0, stream>>>(x, sc_w, sc_b, ac_w, ac_b, oc_w, oc_b,
                                 oc_bn_g, oc_bn_b, oc_bn_m, oc_bn_v, xrfa);
  k_fuse<<<512, 256, 0, stream>>>(x, xrfa, s2, fu_w, fu_b,
                                  fu_bn_g, fu_bn_b, fu_bn_m, fu_bn_v,
                                  (float*)d_out);
}

// Round 5
// 190.308 us; speedup vs baseline: 1.1720x; 1.1720x over previous
//
#include <hip/hip_runtime.h>
#include <math.h>

#define EPS 1e-5f

__device__ __forceinline__ float wave_sum(float v) {
  v += __shfl_down(v, 32);
  v += __shfl_down(v, 16);
  v += __shfl_down(v, 8);
  v += __shfl_down(v, 4);
  v += __shfl_down(v, 2);
  v += __shfl_down(v, 1);
  return v;
}

__device__ __forceinline__ float silu_f(float v) { return v / (1.f + __expf(-v)); }
__device__ __forceinline__ float sigm_f(float v) { return 1.f / (1.f + __expf(-v)); }

__device__ __forceinline__ int bitrev6(int v) {
  return ((v & 1) << 5) | ((v & 2) << 3) | ((v & 4) << 1) |
         ((v & 8) >> 1) | ((v & 16) >> 3) | ((v & 32) >> 5);
}

// ---------------------------------------------------------------------------
// Kernel A: per-(b,c) mean |2D-DFT| + spatial mean (unchanged from R4:
// conjugate-packed row rFFT + column symmetry, kv=0..32 weighted).
// ---------------------------------------------------------------------------
__global__ __launch_bounds__(256) void k_dft(const float* __restrict__ x,
                                             float* __restrict__ energy,
                                             float* __restrict__ meanx) {
  __shared__ float re1[64 * 65];   // [kv natural][h]
  __shared__ float im1[64 * 65];
  __shared__ float redA[4], redB[4];
  const int bc = blockIdx.x;       // b*64 + c
  const int tid = threadIdx.x;
  const int lane = tid & 63;
  const int wv = tid >> 6;         // wave 0..3
  const float* xp = x + (size_t)bc * 4096;

  float twc[6], tws[6];
#pragma unroll
  for (int s = 0; s < 6; ++s) {
    int half = 32 >> s;
    if (lane & half) {
      float ang = -6.283185307179586f * (float)((lane & (half - 1)) << s) / 64.f;
      float sv, cv;
      __sincosf(ang, &sv, &cv);
      twc[s] = cv;
      tws[s] = sv;
    } else {
      twc[s] = 1.f;
      tws[s] = 0.f;
    }
  }

  const int f = bitrev6(lane);
  const int fm = (64 - f) & 63;
  const int plane = bitrev6(fm);

  float lsum = 0.f;
#pragma unroll 1
  for (int rp = 0; rp < 8; ++rp) {
    const int h0 = wv * 16 + rp * 2;
    float zr = xp[h0 * 64 + lane];
    float zi = xp[(h0 + 1) * 64 + lane];
    lsum += zr + zi;
#pragma unroll
    for (int s = 0; s < 6; ++s) {
      const int half = 32 >> s;
      const bool up = (lane & half) != 0;
      float pr = __shfl_xor(zr, half);
      float pi = __shfl_xor(zi, half);
      float tr = up ? pr - zr : zr + pr;
      float ti = up ? pi - zi : zi + pi;
      const float c = twc[s], sn = tws[s];
      zr = tr * c - ti * sn;
      zi = tr * sn + ti * c;
    }
    float mr = __shfl(zr, plane);
    float mi = __shfl(zi, plane);
    float ar = 0.5f * (zr + mr), ai = 0.5f * (zi - mi);
    float br = 0.5f * (zi + mi), bi = 0.5f * (mr - zr);
    re1[f * 65 + h0] = ar;
    im1[f * 65 + h0] = ai;
    re1[f * 65 + h0 + 1] = br;
    im1[f * 65 + h0 + 1] = bi;
  }
  __syncthreads();

  float msum = 0.f;
#pragma unroll 1
  for (int i = 0; i < 9; ++i) {
    const int kv = wv + 4 * i;
    if (kv > 32) break;
    const float wgt = (kv == 0 || kv == 32) ? 1.f : 2.f;
    float ar = re1[kv * 65 + lane];
    float ai = im1[kv * 65 + lane];
#pragma unroll
    for (int s = 0; s < 6; ++s) {
      const int half = 32 >> s;
      const bool up = (lane & half) != 0;
      float pr = __shfl_xor(ar, half);
      float pi = __shfl_xor(ai, half);
      float tr = up ? pr - ar : ar + pr;
      float ti = up ? pi - ai : ai + pi;
      const float c = twc[s], sn = tws[s];
      ar = tr * c - ti * sn;
      ai = tr * sn + ti * c;
    }
    msum += wgt * sqrtf(ar * ar + ai * ai);
  }

  msum = wave_sum(msum);
  lsum = wave_sum(lsum);
  if (lane == 0) { redA[wv] = msum; redB[wv] = lsum; }
  __syncthreads();
  if (tid == 0) {
    float e = redA[0] + redA[1] + redA[2] + redA[3];
    float m = redB[0] + redB[1] + redB[2] + redB[3];
    energy[bc] = e * (1.f / 4096.f);
    meanx[bc] = m * (1.f / 4096.f);
  }
}

// ---------------------------------------------------------------------------
// Kernel B: per-batch channel attention head (unchanged).
// ---------------------------------------------------------------------------
__global__ __launch_bounds__(64) void k_attn(
    const float* __restrict__ energy, const float* __restrict__ meanx,
    const float* __restrict__ ex_w, const float* __restrict__ ey_w,
    const float* __restrict__ ez_w, const float* __restrict__ ff_w,
    const float* __restrict__ ff_b, const float* __restrict__ g1_w,
    const float* __restrict__ g1_b, const float* __restrict__ g2_w,
    const float* __restrict__ g2_b, float* __restrict__ s2) {
  __shared__ float e[64], mx[64], my[64], mz[64];
  __shared__ float ax[64], ay[64], az[64], af[64], h1[16];
  const int b = blockIdx.x;
  const int c = threadIdx.x;
  e[c] = energy[b * 64 + c];
  mx[c] = meanx[b * 64 + c];
  __syncthreads();
  int rank = 0;
  float ec = e[c];
  for (int i = 0; i < 64; ++i) {
    float ei = e[i];
    rank += (ei > ec) || (ei == ec && i < c);
  }
  float mask = (rank < 32) ? 1.f : 0.f;
  my[c] = mx[c] * mask;
  mz[c] = mx[c] * (1.f - mask);
  __syncthreads();
  {
    float l, r, m;
    l = (c > 0) ? mx[c - 1] : 0.f; m = mx[c]; r = (c < 63) ? mx[c + 1] : 0.f;
    ax[c] = sigm_f(ex_w[0] * l + ex_w[1] * m + ex_w[2] * r);
    l = (c > 0) ? my[c - 1] : 0.f; m = my[c]; r = (c < 63) ? my[c + 1] : 0.f;
    ay[c] = sigm_f(ey_w[0] * l + ey_w[1] * m + ey_w[2] * r);
    l = (c > 0) ? mz[c - 1] : 0.f; m = mz[c]; r = (c < 63) ? mz[c + 1] : 0.f;
    az[c] = sigm_f(ez_w[0] * l + ez_w[1] * m + ez_w[2] * r);
  }
  __syncthreads();
  {
    int g = c >> 4;
    float acc = ff_b[c];
#pragma unroll
    for (int i = 0; i < 32; ++i) {
      int ch = g * 32 + i;
      float v = (ch < 64) ? ay[ch] : az[ch - 64];
      acc = fmaf(v, ff_w[c * 32 + i], acc);
    }
    af[c] = acc;
  }
  __syncthreads();
  if (c < 16) {
    float a = g1_b[c];
#pragma unroll
    for (int i = 0; i < 64; ++i) a = fmaf(af[i], g1_w[c * 128 + i], a);
#pragma unroll
    for (int i = 0; i < 64; ++i) a = fmaf(ax[i], g1_w[c * 128 + 64 + i], a);
    h1[c] = silu_f(a);
  }
  __syncthreads();
  float gv = g2_b[c];
#pragma unroll
  for (int o = 0; o < 16; ++o) gv = fmaf(h1[o], g2_w[c * 16 + o], gv);
  gv = sigm_f(gv);
  s2[b * 64 + c] = gv * af[c] + (1.f - gv) * ax[c];
}

// ---------------------------------------------------------------------------
// Kernel C: fused ReceptiveFieldAttentionConv.
// R4 design: P=2 pixels/thread (vertical pair), 256-thread blocks (256
// blocks = 1/CU), x read straight from global (vmcnt path, L1/L2-served,
// predicated borders), weights float4-packed in LDS (lgkmcnt path):
// scwp stride-12 w/ bias@[9], ocwp stride-12, acw/acb packed. ~21 KB LDS.
// ---------------------------------------------------------------------------
__global__ __launch_bounds__(256) void k_rfa(
    const float* __restrict__ x,
    const float* __restrict__ sc_w, const float* __restrict__ sc_b,
    const float* __restrict__ ac_w, const float* __restrict__ ac_b,
    const float* __restrict__ oc_w, const float* __restrict__ oc_b,
    const float* __restrict__ bn_g, const float* __restrict__ bn_b,
    const float* __restrict__ bn_m, const float* __restrict__ bn_v,
    float* __restrict__ xrfa) {
  __shared__ __align__(16) float scwp[16 * 9 * 12];    // taps 0..8, bias at [9]
  __shared__ __align__(16) float mp[16 * 24];          // acw [0..8], acb [12..20]
  __shared__ __align__(16) float ocwp[16 * 16 * 12];
  const int blk = blockIdx.x;          // 256 blocks: 8 bands x 4 g x 8 b
  const int band = blk & 7;
  const int g = (blk >> 3) & 3;
  const int b = blk >> 5;
  const int tid = threadIdx.x;
  const int lane = tid & 63;
  const int wv = tid >> 6;             // 0..3

  // ---- stage packed weights (once per block) ----
  for (int i = tid; i < 1296; i += 256) {
    int icg = i / 81, rem = i - icg * 81;
    int j = rem / 9, t = rem - j * 9;
    scwp[icg * 108 + j * 12 + t] = sc_w[(g * 144 + icg * 9 + j) * 9 + t];
  }
  if (tid < 144) {
    int icg = tid / 9, j = tid - icg * 9;
    scwp[icg * 108 + j * 12 + 9] = sc_b[g * 144 + tid];
    mp[icg * 24 + j] = ac_w[g * 144 + tid];
    mp[icg * 24 + 12 + j] = ac_b[g * 144 + tid];
  }
  for (int i = tid; i < 2304; i += 256) {
    int oco = i / 144, rem = i - oco * 144;
    int icg = rem / 9, j = rem - icg * 9;
    ocwp[icg * 192 + oco * 12 + j] = oc_w[((g * 16 + oco) * 16 + icg) * 9 + j];
  }
  __syncthreads();

  // thread -> rows r0, r0+1 ; col = lane
  const int r0 = band * 8 + wv * 2;
  const int w = lane;
  const bool vW = w > 0, vE = w < 63;
  float acc0[16], acc1[16];
#pragma unroll
  for (int i = 0; i < 16; ++i) { acc0[i] = 0.f; acc1[i] = 0.f; }

  const float* xg = x + ((size_t)(b * 64 + g * 16)) * 4096 + w;

#pragma unroll 1
  for (int icg = 0; icg < 16; ++icg) {
    const float* xc = xg + icg * 4096;
    float n[12];
#pragma unroll
    for (int t = 0; t < 4; ++t) {
      int h = r0 - 1 + t;
      bool vh = (h >= 0) && (h < 64);
      const float* row = xc + h * 64;
      n[t * 3 + 0] = (vh && vW) ? row[-1] : 0.f;
      n[t * 3 + 1] = vh ? row[0] : 0.f;
      n[t * 3 + 2] = (vh && vE) ? row[1] : 0.f;
    }
    float rs0 = n[0] + n[1] + n[2];
    float rs1 = n[3] + n[4] + n[5];
    float rs2 = n[6] + n[7] + n[8];
    float rs3 = n[9] + n[10] + n[11];
    float ap0 = (rs0 + rs1 + rs2) * (1.f / 9.f);
    float ap1 = (rs1 + rs2 + rs3) * (1.f / 9.f);

    float aw[12], ab[12];
    *(float4*)&aw[0] = *(const float4*)&mp[icg * 24];
    *(float4*)&aw[4] = *(const float4*)&mp[icg * 24 + 4];
    *(float4*)&aw[8] = *(const float4*)&mp[icg * 24 + 8];
    *(float4*)&ab[0] = *(const float4*)&mp[icg * 24 + 12];
    *(float4*)&ab[4] = *(const float4*)&mp[icg * 24 + 16];
    *(float4*)&ab[8] = *(const float4*)&mp[icg * 24 + 20];

    float f0[9], f1[9], a0[9], a1[9];
    float amax0 = -1e30f, amax1 = -1e30f;
#pragma unroll
    for (int j = 0; j < 9; ++j) {
      float wt[12];
      *(float4*)&wt[0] = *(const float4*)&scwp[icg * 108 + j * 12];
      *(float4*)&wt[4] = *(const float4*)&scwp[icg * 108 + j * 12 + 4];
      *(float4*)&wt[8] = *(const float4*)&scwp[icg * 108 + j * 12 + 8];
      float p0 = wt[9], p1 = wt[9];
#pragma unroll
      for (int t = 0; t < 9; ++t) {
        p0 = fmaf(n[t], wt[t], p0);       // rows 0..2
        p1 = fmaf(n[t + 3], wt[t], p1);   // rows 1..3
      }
      f0[j] = silu_f(p0);
      f1[j] = silu_f(p1);
      float v0 = fmaf(ap0, aw[j], ab[j]);
      float v1 = fmaf(ap1, aw[j], ab[j]);
      a0[j] = v0; a1[j] = v1;
      amax0 = fmaxf(amax0, v0);
      amax1 = fmaxf(amax1, v1);
    }
    float es0 = 0.f, es1 = 0.f;
    float p0[9], p1[9];
#pragma unroll
    for (int j = 0; j < 9; ++j) {
      float e0 = __expf(a0[j] - amax0);
      float e1 = __expf(a1[j] - amax1);
      es0 += e0; es1 += e1;
      p0[j] = f0[j] * e0;
      p1[j] = f1[j] * e1;
    }
    float i0 = __fdividef(1.f, es0);
    float i1 = __fdividef(1.f, es1);
#pragma unroll
    for (int j = 0; j < 9; ++j) { p0[j] *= i0; p1[j] *= i1; }

#pragma unroll
    for (int oco = 0; oco < 16; ++oco) {
      float ov[12];
      *(float4*)&ov[0] = *(const float4*)&ocwp[icg * 192 + oco * 12];
      *(float4*)&ov[4] = *(const float4*)&ocwp[icg * 192 + oco * 12 + 4];
      *(float4*)&ov[8] = *(const float4*)&ocwp[icg * 192 + oco * 12 + 8];
      float s0 = 0.f, s1 = 0.f;
#pragma unroll
      for (int j = 0; j < 9; ++j) {
        s0 = fmaf(p0[j], ov[j], s0);
        s1 = fmaf(p1[j], ov[j], s1);
      }
      acc0[oco] += s0;
      acc1[oco] += s1;
    }
  }

  float* op = xrfa + ((size_t)(b * 64 + g * 16)) * 4096 + r0 * 64 + w;
#pragma unroll
  for (int oco = 0; oco < 16; ++oco) {
    int oc = g * 16 + oco;
    float s = bn_g[oc] * rsqrtf(bn_v[oc] + EPS);
    float bb = bn_b[oc] - bn_m[oc] * s;
    float ob = oc_b[oc];
    float v0 = fmaf(acc0[oco] + ob, s, bb);
    float v1 = fmaf(acc1[oco] + ob, s, bb);
    op[oco * 4096] = silu_f(v0);
    op[oco * 4096 + 64] = silu_f(v1);
  }
}

// ---------------------------------------------------------------------------
// Kernel D: final 1x1 conv + BN + SiLU.
// R4: fu_w staged to LDS once, read as float4 broadcasts (removes the
// wave-uniform global/scalar-load flood of the previous version).
// ---------------------------------------------------------------------------
__global__ __launch_bounds__(256) void k_fuse(
    const float* __restrict__ x, const float* __restrict__ xrfa,
    const float* __restrict__ s2, const float* __restrict__ fu_w,
    const float* __restrict__ fu_b, const float* __restrict__ bn_g,
    const float* __restrict__ bn_b, const float* __restrict__ bn_m,
    const float* __restrict__ bn_v, float* __restrict__ out) {
  __shared__ float red[3 * 64 * 33];
  __shared__ __align__(16) float fw[4096];
  const int blk = blockIdx.x;
  const int tid = threadIdx.x;
  const int sloc = tid & 63;
  const int chunk = __builtin_amdgcn_readfirstlane(tid >> 6);
  const int b = blk >> 6;
  const int sp = (blk & 63) * 64 + sloc;
  const int cb = (chunk & 1) * 32;
  const int wb = chunk * 32;

  for (int i = tid; i < 1024; i += 256)
    ((float4*)fw)[i] = ((const float4*)fu_w)[i];

  const float* src = (chunk < 2) ? xrfa : x;
  const float* ip = src + ((size_t)(b * 64 + cb)) * 4096 + sp;
  float inv[32];
  if (chunk < 2) {
#pragma unroll
    for (int i = 0; i < 32; ++i) inv[i] = ip[i * 4096];
  } else {
#pragma unroll
    for (int i = 0; i < 32; ++i) inv[i] = ip[i * 4096] * s2[b * 64 + cb + i];
  }
  __syncthreads();

  float acc[32];
#pragma unroll
  for (int oc = 0; oc < 32; ++oc) {
    const float* wr = &fw[oc * 128 + wb];
    float a = 0.f;
#pragma unroll
    for (int q = 0; q < 8; ++q) {
      float4 wv4 = *(const float4*)&wr[q * 4];
      a = fmaf(inv[q * 4 + 0], wv4.x, a);
      a = fmaf(inv[q * 4 + 1], wv4.y, a);
      a = fmaf(inv[q * 4 + 2], wv4.z, a);
      a = fmaf(inv[q * 4 + 3], wv4.w, a);
    }
    acc[oc] = a;
  }

  if (chunk != 0) {
    float* rp = &red[(chunk - 1) * 2112 + sloc * 33];
#pragma unroll
    for (int oc = 0; oc < 32; ++oc) rp[oc] = acc[oc];
  }
  __syncthreads();
  if (chunk == 0) {
#pragma unroll
    for (int oc = 0; oc < 32; ++oc)
      acc[oc] += red[sloc * 33 + oc] + red[2112 + sloc * 33 + oc] +
                 red[4224 + sloc * 33 + oc];
    float* op = out + ((size_t)b * 32) * 4096 + sp;
#pragma unroll
    for (int oc = 0; oc < 32; ++oc) {
      float s = bn_g[oc] * rsqrtf(bn_v[oc] + EPS);
      float v = acc[oc] + fu_b[oc];
      v = fmaf(v, s, bn_b[oc] - bn_m[oc] * s);
      op[oc * 4096] = silu_f(v);
    }
  }
}

extern "C" void kernel_launch(void* const* d_in, const int* in_sizes, int n_in,
                              void* d_out, int out_size, void* d_ws, size_t ws_size,
                              hipStream_t stream) {
  const float* x       = (const float*)d_in[0];
  const float* sc_w    = (const float*)d_in[1];
  const float* sc_b    = (const float*)d_in[2];
  const float* ac_w    = (const float*)d_in[3];
  const float* ac_b    = (const float*)d_in[4];
  const float* oc_w    = (const float*)d_in[5];
  const float* oc_b    = (const float*)d_in[6];
  const float* oc_bn_g = (const float*)d_in[7];
  const float* oc_bn_b = (const float*)d_in[8];
  const float* oc_bn_m = (const float*)d_in[9];
  const float* oc_bn_v = (const float*)d_in[10];
  const float* ex_w    = (const float*)d_in[11];
  const float* ey_w    = (const float*)d_in[12];
  const float* ez_w    = (const float*)d_in[13];
  const float* ff_w    = (const float*)d_in[14];
  const float* ff_b    = (const float*)d_in[15];
  const float* g1_w    = (const float*)d_in[16];
  const float* g1_b    = (const float*)d_in[17];
  const float* g2_w    = (const float*)d_in[18];
  const float* g2_b    = (const float*)d_in[19];
  const float* fu_w    = (const float*)d_in[20];
  const float* fu_b    = (const float*)d_in[21];
  const float* fu_bn_g = (const float*)d_in[22];
  const float* fu_bn_b = (const float*)d_in[23];
  const float* fu_bn_m = (const float*)d_in[24];
  const float* fu_bn_v = (const float*)d_in[25];

  float* ws     = (float*)d_ws;
  float* energy = ws;            // 512 floats
  float* meanx  = ws + 512;      // 512 floats
  float* s2     = ws + 1024;     // 512 floats
  float* xrfa   = ws + 2048;     // 8*64*4096 floats

  k_dft<<<512, 256, 0, stream>>>(x, energy, meanx);
  k_attn<<<8, 64, 0, stream>>>(energy, meanx, ex_w, ey_w, ez_w,
                               ff_w, ff_b, g1_w, g1_b, g2_w, g2_b, s2);
  k_rfa<<<256, 256, 0, stream>>>(x, sc_w, sc_b, ac_w, ac_b, oc_w, oc_b,
                                 oc_bn_g, oc_bn_b, oc_bn_m, oc_bn_v, xrfa);
  k_fuse<<<512, 256, 0, stream>>>(x, xrfa, s2, fu_w, fu_b,
                                  fu_bn_g, fu_bn_b, fu_bn_m, fu_bn_v,
                                  (float*)d_out);
}

// Round 6
// 174.086 us; speedup vs baseline: 1.2812x; 1.0932x over previous
//
#include <hip/hip_runtime.h>
#include <math.h>

#define EPS 1e-5f

__device__ __forceinline__ float wave_sum(float v) {
  v += __shfl_down(v, 32);
  v += __shfl_down(v, 16);
  v += __shfl_down(v, 8);
  v += __shfl_down(v, 4);
  v += __shfl_down(v, 2);
  v += __shfl_down(v, 1);
  return v;
}

__device__ __forceinline__ float silu_f(float v) { return v / (1.f + __expf(-v)); }
__device__ __forceinline__ float sigm_f(float v) { return 1.f / (1.f + __expf(-v)); }

__device__ __forceinline__ int bitrev6(int v) {
  return ((v & 1) << 5) | ((v & 2) << 3) | ((v & 4) << 1) |
         ((v & 8) >> 1) | ((v & 16) >> 3) | ((v & 32) >> 5);
}

#define FFT6(zr, zi)                                           \
  do {                                                         \
    _Pragma("unroll") for (int s = 0; s < 6; ++s) {            \
      const int half = 32 >> s;                                \
      const bool up = (lane & half) != 0;                      \
      float pr = __shfl_xor(zr, half);                         \
      float pi = __shfl_xor(zi, half);                         \
      float tr = up ? pr - zr : zr + pr;                       \
      float ti = up ? pi - zi : zi + pi;                       \
      const float c = twc[s], sn = tws[s];                     \
      zr = tr * c - ti * sn;                                   \
      zi = tr * sn + ti * c;                                   \
    }                                                          \
  } while (0)

// ---------------------------------------------------------------------------
// Kernel A: per-(b,c) mean |2D-DFT| + spatial mean.
// R5: 2 independent conj-packed FFT chains per iteration (ILP for the 6-stage
// shuffle dependency at 2 waves/SIMD); LDS holds only kv<=32 (17 KB).
// ---------------------------------------------------------------------------
__global__ __launch_bounds__(256) void k_dft(const float* __restrict__ x,
                                             float* __restrict__ energy,
                                             float* __restrict__ meanx) {
  __shared__ float re1[33 * 65];   // [kv 0..32][h]
  __shared__ float im1[33 * 65];
  __shared__ float redA[4], redB[4];
  const int bc = blockIdx.x;       // b*64 + c
  const int tid = threadIdx.x;
  const int lane = tid & 63;
  const int wv = tid >> 6;         // wave 0..3
  const float* xp = x + (size_t)bc * 4096;

  float twc[6], tws[6];
#pragma unroll
  for (int s = 0; s < 6; ++s) {
    int half = 32 >> s;
    if (lane & half) {
      float ang = -6.283185307179586f * (float)((lane & (half - 1)) << s) / 64.f;
      float sv, cv;
      __sincosf(ang, &sv, &cv);
      twc[s] = cv;
      tws[s] = sv;
    } else {
      twc[s] = 1.f;
      tws[s] = 0.f;
    }
  }

  const int f = bitrev6(lane);
  const int fm = (64 - f) & 63;
  const int plane = bitrev6(fm);

  // ---- row pass: 4 rows per iter as 2 independent packed complex FFTs ----
  float lsum = 0.f;
#pragma unroll 1
  for (int rp = 0; rp < 4; ++rp) {
    const int h0 = wv * 16 + rp * 4;
    float x0 = xp[h0 * 64 + lane];
    float x1 = xp[(h0 + 1) * 64 + lane];
    float x2 = xp[(h0 + 2) * 64 + lane];
    float x3 = xp[(h0 + 3) * 64 + lane];
    lsum += x0 + x1 + x2 + x3;
    float zr = x0, zi = x1, yr = x2, yi = x3;
#pragma unroll
    for (int s = 0; s < 6; ++s) {
      const int half = 32 >> s;
      const bool up = (lane & half) != 0;
      float pzr = __shfl_xor(zr, half);
      float pzi = __shfl_xor(zi, half);
      float pyr = __shfl_xor(yr, half);
      float pyi = __shfl_xor(yi, half);
      float tzr = up ? pzr - zr : zr + pzr;
      float tzi = up ? pzi - zi : zi + pzi;
      float tyr = up ? pyr - yr : yr + pyr;
      float tyi = up ? pyi - yi : yi + pyi;
      const float c = twc[s], sn = tws[s];
      zr = tzr * c - tzi * sn;
      zi = tzr * sn + tzi * c;
      yr = tyr * c - tyi * sn;
      yi = tyr * sn + tyi * c;
    }
    float mzr = __shfl(zr, plane), mzi = __shfl(zi, plane);
    float myr = __shfl(yr, plane), myi = __shfl(yi, plane);
    if (f <= 32) {
      float ar = 0.5f * (zr + mzr), ai = 0.5f * (zi - mzi);
      float br = 0.5f * (zi + mzi), bi = 0.5f * (mzr - zr);
      float cr = 0.5f * (yr + myr), ci = 0.5f * (yi - myi);
      float dr = 0.5f * (yi + myi), di = 0.5f * (myr - yr);
      re1[f * 65 + h0] = ar;     im1[f * 65 + h0] = ai;
      re1[f * 65 + h0 + 1] = br; im1[f * 65 + h0 + 1] = bi;
      re1[f * 65 + h0 + 2] = cr; im1[f * 65 + h0 + 2] = ci;
      re1[f * 65 + h0 + 3] = dr; im1[f * 65 + h0 + 3] = di;
    }
  }
  __syncthreads();

  // ---- column pass: kv=0..31 as 2 independent chains/iter; kv=32 tail ----
  float msum = 0.f;
#pragma unroll 1
  for (int i = 0; i < 4; ++i) {
    const int kv1 = wv + 8 * i;       // <= 27
    const int kv2 = kv1 + 4;          // <= 31
    const float w1 = (kv1 == 0) ? 1.f : 2.f;
    float ar = re1[kv1 * 65 + lane];
    float ai = im1[kv1 * 65 + lane];
    float br = re1[kv2 * 65 + lane];
    float bi = im1[kv2 * 65 + lane];
#pragma unroll
    for (int s = 0; s < 6; ++s) {
      const int half = 32 >> s;
      const bool up = (lane & half) != 0;
      float par = __shfl_xor(ar, half);
      float pai = __shfl_xor(ai, half);
      float pbr = __shfl_xor(br, half);
      float pbi = __shfl_xor(bi, half);
      float tar = up ? par - ar : ar + par;
      float tai = up ? pai - ai : ai + pai;
      float tbr = up ? pbr - br : br + pbr;
      float tbi = up ? pbi - bi : bi + pbi;
      const float c = twc[s], sn = tws[s];
      ar = tar * c - tai * sn;
      ai = tar * sn + tai * c;
      br = tbr * c - tbi * sn;
      bi = tbr * sn + tbi * c;
    }
    msum += w1 * sqrtf(ar * ar + ai * ai) + 2.f * sqrtf(br * br + bi * bi);
  }
  if (wv == 0) {
    float ar = re1[32 * 65 + lane];
    float ai = im1[32 * 65 + lane];
    FFT6(ar, ai);
    msum += sqrtf(ar * ar + ai * ai);
  }

  msum = wave_sum(msum);
  lsum = wave_sum(lsum);
  if (lane == 0) { redA[wv] = msum; redB[wv] = lsum; }
  __syncthreads();
  if (tid == 0) {
    float e = redA[0] + redA[1] + redA[2] + redA[3];
    float m = redB[0] + redB[1] + redB[2] + redB[3];
    energy[bc] = e * (1.f / 4096.f);
    meanx[bc] = m * (1.f / 4096.f);
  }
}

// ---------------------------------------------------------------------------
// Kernel B: per-batch channel attention head (unchanged).
// ---------------------------------------------------------------------------
__global__ __launch_bounds__(64) void k_attn(
    const float* __restrict__ energy, const float* __restrict__ meanx,
    const float* __restrict__ ex_w, const float* __restrict__ ey_w,
    const float* __restrict__ ez_w, const float* __restrict__ ff_w,
    const float* __restrict__ ff_b, const float* __restrict__ g1_w,
    const float* __restrict__ g1_b, const float* __restrict__ g2_w,
    const float* __restrict__ g2_b, float* __restrict__ s2) {
  __shared__ float e[64], mx[64], my[64], mz[64];
  __shared__ float ax[64], ay[64], az[64], af[64], h1[16];
  const int b = blockIdx.x;
  const int c = threadIdx.x;
  e[c] = energy[b * 64 + c];
  mx[c] = meanx[b * 64 + c];
  __syncthreads();
  int rank = 0;
  float ec = e[c];
  for (int i = 0; i < 64; ++i) {
    float ei = e[i];
    rank += (ei > ec) || (ei == ec && i < c);
  }
  float mask = (rank < 32) ? 1.f : 0.f;
  my[c] = mx[c] * mask;
  mz[c] = mx[c] * (1.f - mask);
  __syncthreads();
  {
    float l, r, m;
    l = (c > 0) ? mx[c - 1] : 0.f; m = mx[c]; r = (c < 63) ? mx[c + 1] : 0.f;
    ax[c] = sigm_f(ex_w[0] * l + ex_w[1] * m + ex_w[2] * r);
    l = (c > 0) ? my[c - 1] : 0.f; m = my[c]; r = (c < 63) ? my[c + 1] : 0.f;
    ay[c] = sigm_f(ey_w[0] * l + ey_w[1] * m + ey_w[2] * r);
    l = (c > 0) ? mz[c - 1] : 0.f; m = mz[c]; r = (c < 63) ? mz[c + 1] : 0.f;
    az[c] = sigm_f(ez_w[0] * l + ez_w[1] * m + ez_w[2] * r);
  }
  __syncthreads();
  {
    int g = c >> 4;
    float acc = ff_b[c];
#pragma unroll
    for (int i = 0; i < 32; ++i) {
      int ch = g * 32 + i;
      float v = (ch < 64) ? ay[ch] : az[ch - 64];
      acc = fmaf(v, ff_w[c * 32 + i], acc);
    }
    af[c] = acc;
  }
  __syncthreads();
  if (c < 16) {
    float a = g1_b[c];
#pragma unroll
    for (int i = 0; i < 64; ++i) a = fmaf(af[i], g1_w[c * 128 + i], a);
#pragma unroll
    for (int i = 0; i < 64; ++i) a = fmaf(ax[i], g1_w[c * 128 + 64 + i], a);
    h1[c] = silu_f(a);
  }
  __syncthreads();
  float gv = g2_b[c];
#pragma unroll
  for (int o = 0; o < 16; ++o) gv = fmaf(h1[o], g2_w[c * 16 + o], gv);
  gv = sigm_f(gv);
  s2[b * 64 + c] = gv * af[c] + (1.f - gv) * ax[c];
}

// ---------------------------------------------------------------------------
// Kernel C: fused ReceptiveFieldAttentionConv.
// R5: intra-block icg split. Waves 0-1 process icg 0-7, waves 2-3 icg 8-15
// for the SAME pixels; stride-33 LDS merge, epilogue on waves 0-1. Doubles
// wave count (8 waves/CU = 2/SIMD) at constant total LDS-broadcast traffic,
// so the ~26 us LDS-pipe and ~25 us VALU can finally overlap.
// Block 256 thr (4 waves) covers 4 rows; grid 512 = 8b x 4g x 16 bands.
// ---------------------------------------------------------------------------
__global__ __launch_bounds__(256) void k_rfa(
    const float* __restrict__ x,
    const float* __restrict__ sc_w, const float* __restrict__ sc_b,
    const float* __restrict__ ac_w, const float* __restrict__ ac_b,
    const float* __restrict__ oc_w, const float* __restrict__ oc_b,
    const float* __restrict__ bn_g, const float* __restrict__ bn_b,
    const float* __restrict__ bn_m, const float* __restrict__ bn_v,
    float* __restrict__ xrfa) {
  __shared__ __align__(16) float scwp[16 * 9 * 12];    // taps 0..8, bias at [9]
  __shared__ __align__(16) float mp[16 * 24];          // acw [0..8], acb [12..20]
  __shared__ __align__(16) float ocwp[16 * 16 * 12];
  __shared__ float red[128 * 33];                      // half-1 partials
  const int blk = blockIdx.x;          // 512 blocks
  const int band = blk & 15;
  const int g = (blk >> 4) & 3;
  const int b = blk >> 6;
  const int tid = threadIdx.x;
  const int lane = tid & 63;
  const int wv = tid >> 6;             // 0..3
  const int wp = wv & 1;               // row-pair within band
  const int half = wv >> 1;            // icg half

  // ---- stage packed weights (full 16-icg set, once per block) ----
  for (int i = tid; i < 1296; i += 256) {
    int icg = i / 81, rem = i - icg * 81;
    int j = rem / 9, t = rem - j * 9;
    scwp[icg * 108 + j * 12 + t] = sc_w[(g * 144 + icg * 9 + j) * 9 + t];
  }
  if (tid < 144) {
    int icg = tid / 9, j = tid - icg * 9;
    scwp[icg * 108 + j * 12 + 9] = sc_b[g * 144 + tid];
    mp[icg * 24 + j] = ac_w[g * 144 + tid];
    mp[icg * 24 + 12 + j] = ac_b[g * 144 + tid];
  }
  for (int i = tid; i < 2304; i += 256) {
    int oco = i / 144, rem = i - oco * 144;
    int icg = rem / 9, j = rem - icg * 9;
    ocwp[icg * 192 + oco * 12 + j] = oc_w[((g * 16 + oco) * 16 + icg) * 9 + j];
  }
  __syncthreads();

  const int r0 = band * 4 + wp * 2;
  const int w = lane;
  const bool vW = w > 0, vE = w < 63;
  float acc0[16], acc1[16];
#pragma unroll
  for (int i = 0; i < 16; ++i) { acc0[i] = 0.f; acc1[i] = 0.f; }

  const float* xg = x + ((size_t)(b * 64 + g * 16)) * 4096 + w;
  const int icg0 = half * 8;

#pragma unroll 1
  for (int ii = 0; ii < 8; ++ii) {
    const int icg = icg0 + ii;
    const float* xc = xg + icg * 4096;
    float n[12];
#pragma unroll
    for (int t = 0; t < 4; ++t) {
      int h = r0 - 1 + t;
      bool vh = (h >= 0) && (h < 64);
      const float* row = xc + h * 64;
      n[t * 3 + 0] = (vh && vW) ? row[-1] : 0.f;
      n[t * 3 + 1] = vh ? row[0] : 0.f;
      n[t * 3 + 2] = (vh && vE) ? row[1] : 0.f;
    }
    float rs0 = n[0] + n[1] + n[2];
    float rs1 = n[3] + n[4] + n[5];
    float rs2 = n[6] + n[7] + n[8];
    float rs3 = n[9] + n[10] + n[11];
    float ap0 = (rs0 + rs1 + rs2) * (1.f / 9.f);
    float ap1 = (rs1 + rs2 + rs3) * (1.f / 9.f);

    float aw[12], ab[12];
    *(float4*)&aw[0] = *(const float4*)&mp[icg * 24];
    *(float4*)&aw[4] = *(const float4*)&mp[icg * 24 + 4];
    *(float4*)&aw[8] = *(const float4*)&mp[icg * 24 + 8];
    *(float4*)&ab[0] = *(const float4*)&mp[icg * 24 + 12];
    *(float4*)&ab[4] = *(const float4*)&mp[icg * 24 + 16];
    *(float4*)&ab[8] = *(const float4*)&mp[icg * 24 + 20];

    float f0[9], f1[9], a0[9], a1[9];
    float amax0 = -1e30f, amax1 = -1e30f;
#pragma unroll
    for (int j = 0; j < 9; ++j) {
      float wt[12];
      *(float4*)&wt[0] = *(const float4*)&scwp[icg * 108 + j * 12];
      *(float4*)&wt[4] = *(const float4*)&scwp[icg * 108 + j * 12 + 4];
      *(float4*)&wt[8] = *(const float4*)&scwp[icg * 108 + j * 12 + 8];
      float p0 = wt[9], p1 = wt[9];
#pragma unroll
      for (int t = 0; t < 9; ++t) {
        p0 = fmaf(n[t], wt[t], p0);       // rows 0..2
        p1 = fmaf(n[t + 3], wt[t], p1);   // rows 1..3
      }
      f0[j] = silu_f(p0);
      f1[j] = silu_f(p1);
      float v0 = fmaf(ap0, aw[j], ab[j]);
      float v1 = fmaf(ap1, aw[j], ab[j]);
      a0[j] = v0; a1[j] = v1;
      amax0 = fmaxf(amax0, v0);
      amax1 = fmaxf(amax1, v1);
    }
    float es0 = 0.f, es1 = 0.f;
    float p0[9], p1[9];
#pragma unroll
    for (int j = 0; j < 9; ++j) {
      float e0 = __expf(a0[j] - amax0);
      float e1 = __expf(a1[j] - amax1);
      es0 += e0; es1 += e1;
      p0[j] = f0[j] * e0;
      p1[j] = f1[j] * e1;
    }
    float i0 = __fdividef(1.f, es0);
    float i1 = __fdividef(1.f, es1);
#pragma unroll
    for (int j = 0; j < 9; ++j) { p0[j] *= i0; p1[j] *= i1; }

#pragma unroll
    for (int oco = 0; oco < 16; ++oco) {
      float ov[12];
      *(float4*)&ov[0] = *(const float4*)&ocwp[icg * 192 + oco * 12];
      *(float4*)&ov[4] = *(const float4*)&ocwp[icg * 192 + oco * 12 + 4];
      *(float4*)&ov[8] = *(const float4*)&ocwp[icg * 192 + oco * 12 + 8];
      float s0 = 0.f, s1 = 0.f;
#pragma unroll
      for (int j = 0; j < 9; ++j) {
        s0 = fmaf(p0[j], ov[j], s0);
        s1 = fmaf(p1[j], ov[j], s1);
      }
      acc0[oco] += s0;
      acc1[oco] += s1;
    }
  }

  // ---- merge the two icg halves (stride-33: banks (rid+k)%32, free) ----
  const int rid = wp * 64 + lane;
  if (half == 1) {
#pragma unroll
    for (int k = 0; k < 16; ++k) {
      red[rid * 33 + k] = acc0[k];
      red[rid * 33 + 16 + k] = acc1[k];
    }
  }
  __syncthreads();
  if (half == 0) {
#pragma unroll
    for (int k = 0; k < 16; ++k) {
      acc0[k] += red[rid * 33 + k];
      acc1[k] += red[rid * 33 + 16 + k];
    }
    float* op = xrfa + ((size_t)(b * 64 + g * 16)) * 4096 + r0 * 64 + w;
#pragma unroll
    for (int oco = 0; oco < 16; ++oco) {
      int oc = g * 16 + oco;
      float s = bn_g[oc] * rsqrtf(bn_v[oc] + EPS);
      float bb = bn_b[oc] - bn_m[oc] * s;
      float ob = oc_b[oc];
      float v0 = fmaf(acc0[oco] + ob, s, bb);
      float v1 = fmaf(acc1[oco] + ob, s, bb);
      op[oco * 4096] = silu_f(v0);
      op[oco * 4096 + 64] = silu_f(v1);
    }
  }
}

// ---------------------------------------------------------------------------
// Kernel D: final 1x1 conv + BN + SiLU.
// R5: oc-split (thread = site x oc-octet, all 128 inputs in VGPRs) — no
// cross-thread reduction, no red buffer. 512 blocks, 8 waves/CU.
// ---------------------------------------------------------------------------
__global__ __launch_bounds__(256) void k_fuse(
    const float* __restrict__ x, const float* __restrict__ xrfa,
    const float* __restrict__ s2, const float* __restrict__ fu_w,
    const float* __restrict__ fu_b, const float* __restrict__ bn_g,
    const float* __restrict__ bn_b, const float* __restrict__ bn_m,
    const float* __restrict__ bn_v, float* __restrict__ out) {
  __shared__ __align__(16) float fw[4096];
  __shared__ float s2l[64];
  const int blk = blockIdx.x;          // 512 blocks
  const int tid = threadIdx.x;
  const int sloc = tid & 63;
  const int ocq = tid >> 6;            // oc octet 0..3
  const int b = blk >> 6;
  const int sp = (blk & 63) * 64 + sloc;

  for (int i = tid; i < 1024; i += 256)
    ((float4*)fw)[i] = ((const float4*)fu_w)[i];
  if (tid < 64) s2l[tid] = s2[b * 64 + tid];

  const float* xr = xrfa + (size_t)b * 64 * 4096 + sp;
  const float* xp = x + (size_t)b * 64 * 4096 + sp;
  float va[64], vb[64];
#pragma unroll
  for (int i = 0; i < 64; ++i) va[i] = xr[i * 4096];
#pragma unroll
  for (int i = 0; i < 64; ++i) vb[i] = xp[i * 4096];
  __syncthreads();
#pragma unroll
  for (int i = 0; i < 64; ++i) vb[i] *= s2l[i];

  float* op = out + (size_t)b * 32 * 4096 + sp;
#pragma unroll 1
  for (int o = 0; o < 8; ++o) {
    const int oc = ocq * 8 + o;
    const float* wr = &fw[oc * 128];
    float a = 0.f;
#pragma unroll
    for (int q = 0; q < 16; ++q) {
      float4 w4 = *(const float4*)&wr[q * 4];
      a = fmaf(va[q * 4 + 0], w4.x, a);
      a = fmaf(va[q * 4 + 1], w4.y, a);
      a = fmaf(va[q * 4 + 2], w4.z, a);
      a = fmaf(va[q * 4 + 3], w4.w, a);
    }
#pragma unroll
    for (int q = 0; q < 16; ++q) {
      float4 w4 = *(const float4*)&wr[64 + q * 4];
      a = fmaf(vb[q * 4 + 0], w4.x, a);
      a = fmaf(vb[q * 4 + 1], w4.y, a);
      a = fmaf(vb[q * 4 + 2], w4.z, a);
      a = fmaf(vb[q * 4 + 3], w4.w, a);
    }
    float s = bn_g[oc] * rsqrtf(bn_v[oc] + EPS);
    float v = a + fu_b[oc];
    v = fmaf(v, s, bn_b[oc] - bn_m[oc] * s);
    op[oc * 4096] = silu_f(v);
  }
}

extern "C" void kernel_launch(void* const* d_in, const int* in_sizes, int n_in,
                              void* d_out, int out_size, void* d_ws, size_t ws_size,
                              hipStream_t stream) {
  const float* x       = (const float*)d_in[0];
  const float* sc_w    = (const float*)d_in[1];
  const float* sc_b    = (const float*)d_in[2];
  const float* ac_w    = (const float*)d_in[3];
  const float* ac_b    = (const float*)d_in[4];
  const float* oc_w    = (const float*)d_in[5];
  const float* oc_b    = (const float*)d_in[6];
  const float* oc_bn_g = (const float*)d_in[7];
  const float* oc_bn_b = (const float*)d_in[8];
  const float* oc_bn_m = (const float*)d_in[9];
  const float* oc_bn_v = (const float*)d_in[10];
  const float* ex_w    = (const float*)d_in[11];
  const float* ey_w    = (const float*)d_in[12];
  const float* ez_w    = (const float*)d_in[13];
  const float* ff_w    = (const float*)d_in[14];
  const float* ff_b    = (const float*)d_in[15];
  const float* g1_w    = (const float*)d_in[16];
  const float* g1_b    = (const float*)d_in[17];
  const float* g2_w    = (const float*)d_in[18];
  const float* g2_b    = (const float*)d_in[19];
  const float* fu_w    = (const float*)d_in[20];
  const float* fu_b    = (const float*)d_in[21];
  const float* fu_bn_g = (const float*)d_in[22];
  const float* fu_bn_b = (const float*)d_in[23];
  const float* fu_bn_m = (const float*)d_in[24];
  const float* fu_bn_v = (const float*)d_in[25];

  float* ws     = (float*)d_ws;
  float* energy = ws;            // 512 floats
  float* meanx  = ws + 512;      // 512 floats
  float* s2     = ws + 1024;     // 512 floats
  float* xrfa   = ws + 2048;     // 8*64*4096 floats

  k_dft<<<512, 256, 0, stream>>>(x, energy, meanx);
  k_attn<<<8, 64, 0, stream>>>(energy, meanx, ex_w, ey_w, ez_w,
                               ff_w, ff_b, g1_w, g1_b, g2_w, g2_b, s2);
  k_rfa<<<512, 256, 0, stream>>>(x, sc_w, sc_b, ac_w, ac_b, oc_w, oc_b,
                                 oc_bn_g, oc_bn_b, oc_bn_m, oc_bn_v, xrfa);
  k_fuse<<<512, 256, 0, stream>>>(x, xrfa, s2, fu_w, fu_b,
                                  fu_bn_g, fu_bn_b, fu_bn_m, fu_bn_v,
                                  (float*)d_out);
}